// Round 9
// baseline (1139.996 us; speedup 1.0000x reference)
//
#include <hip/hip_runtime.h>

#define BS 512
#define SL 1024
#define NC 64

// ---------------------------------------------------------------------------
// Cross-lane helpers (epilogue only)
// ---------------------------------------------------------------------------
template <int CTRL>
__device__ __forceinline__ float dppf(float x) {
    return __int_as_float(__builtin_amdgcn_mov_dpp(__float_as_int(x), CTRL, 0xF, 0xF, true));
}
__device__ __forceinline__ float rflf(float x) {
    return __int_as_float(__builtin_amdgcn_readfirstlane(__float_as_int(x)));
}
__device__ __forceinline__ void halfswap32(float x, float& r0, float& r1) {
#if __has_builtin(__builtin_amdgcn_permlane32_swap)
    auto r = __builtin_amdgcn_permlane32_swap(__float_as_int(x), __float_as_int(x), false, false);
    r0 = __int_as_float(r[0]); r1 = __int_as_float(r[1]);
#else
    float w = __shfl_xor(x, 32, 64);
    bool up = (threadIdx.x & 32) != 0;
    r0 = up ? w : x; r1 = up ? x : w;
#endif
}
__device__ __forceinline__ void halfswap16(float x, float& r0, float& r1) {
#if __has_builtin(__builtin_amdgcn_permlane16_swap)
    auto r = __builtin_amdgcn_permlane16_swap(__float_as_int(x), __float_as_int(x), false, false);
    r0 = __int_as_float(r[0]); r1 = __int_as_float(r[1]);
#else
    float w = __int_as_float(__builtin_amdgcn_ds_swizzle(__float_as_int(x), 0x401F)); // xor16
    bool up = (threadIdx.x & 16) != 0;
    r0 = up ? w : x; r1 = up ? x : w;
#endif
}
__device__ __forceinline__ float wave_sum(float x) {
    x += dppf<0xB1>(x);   // xor1
    x += dppf<0x4E>(x);   // xor2
    x += dppf<0x141>(x);  // xor7
    x += dppf<0x140>(x);  // xor15
    float a, c;
    halfswap16(x, a, c); x = a + c;
    halfswap32(x, a, c); x = a + c;
    return x;
}

// ---------------------------------------------------------------------------
// Kernel 1: out[0] = 0 (loss acc), out[1..4096] = transitions copy
// ---------------------------------------------------------------------------
__global__ __launch_bounds__(256) void crf_init_out(const float* __restrict__ trans,
                                                    float* __restrict__ out) {
    int idx = blockIdx.x * 256 + threadIdx.x;
    if (idx == 0) out[0] = 0.0f;
    if (idx < NC * NC) out[1 + idx] = trans[idx];
}

// ---------------------------------------------------------------------------
// Kernel 2: unary + binary score sums (fully parallel). Adds -(u+b)/BS to out.
// ---------------------------------------------------------------------------
__global__ __launch_bounds__(256) void crf_ub(const float* __restrict__ inputs,
                                              const int* __restrict__ masks,
                                              const int* __restrict__ tags,
                                              const float* __restrict__ trans,
                                              float* __restrict__ out) {
    const int b = blockIdx.x;
    const int tid = threadIdx.x;
    const int* tg = tags + (size_t)b * SL;
    const int* mk = masks + (size_t)b * SL;
    const float* xb = inputs + (size_t)b * SL * NC;

    float acc = 0.0f;
    const int t0 = tid * 4;
    int tprev = (t0 > 0) ? tg[t0 - 1] : 0;
#pragma unroll
    for (int j = 0; j < 4; ++j) {
        int t = t0 + j;
        int tgt = tg[t];
        if (mk[t] == 0) {
            acc += xb[(size_t)t * NC + tgt];
            if (t > 0) acc += trans[tprev * NC + tgt];
        }
        tprev = tgt;
    }
    acc = wave_sum(acc);
    __shared__ float r[4];
    if ((tid & 63) == 0) r[tid >> 6] = acc;
    __syncthreads();
    if (tid == 0) atomicAdd(out, -(r[0] + r[1] + r[2] + r[3]) * (1.0f / BS));
}

// ---------------------------------------------------------------------------
// Kernel 3: forward recurrence. One wave per batch, lane c owns class c.
//   q'_c = (sum_i q_i * E[i][c]) * exp(x_c) / m,   base += log(m)
//
// LDS layout (single wave -> no barriers, only waitcnt ordering):
//  * E: row c at dword 64*c; 16B-granule G stored at position G^(c&7)
//    (XOR swizzle: fixes the 256B-stride ds_read_b128 bank conflict).
//  * q: 8 copies; copy k at dword 4096+68*k; logical granule g at position g^k.
//  Lane c (k=c&7) reads BOTH E and q at immediate position j -> both hold
//  logical granule j^k -> static fma pairing, sum over j is complete.
// ---------------------------------------------------------------------------
__global__ __launch_bounds__(64)
void crf_fwd(const float* __restrict__ inputs,
             const int* __restrict__ masks,
             const float* __restrict__ trans,
             float* __restrict__ out) {
    const int b = blockIdx.x;
    const int lane = threadIdx.x;
    const int k7 = lane & 7;
    const float* __restrict__ xp = inputs + (size_t)b * SL * NC;

    __shared__ float lds[64 * 64 + 8 * 68];   // 18560 B

    // ---- len = lengths[b] via ballot popcount (masks monotone)
    int len = 0;
#pragma unroll
    for (int k = 0; k < SL / NC; ++k) {
        unsigned long long bal = __ballot(masks[(size_t)b * SL + k * NC + lane] == 0);
        len += __popcll(bal);
    }

    // ---- init E rows (lane c writes its own column of exp(T), swizzled)
#pragma unroll
    for (int G = 0; G < 16; ++G) {
        int pos = G ^ k7;
#pragma unroll
        for (int e = 0; e < 4; ++e)
            lds[64 * lane + 4 * pos + e] = __expf(trans[(4 * G + e) * NC + lane]);
    }

    // ---- q publish addresses (loop-invariant): copy k, granule (lane>>2)^k
    int qaddr[8];
    {
        int g = lane >> 2, e = lane & 3;
#pragma unroll
        for (int k = 0; k < 8; ++k)
            qaddr[k] = 64 * 64 + 68 * k + 4 * (g ^ k) + e;
    }
    const float* Erow = &lds[64 * lane];
    const float* Qrow = &lds[64 * 64 + 68 * k7];

    __syncthreads();   // init visible (single wave; cheap)

    // ---- t = 0
    float x0 = xp[lane];
    float base = rflf(x0);
    float q = __expf(x0 - base);

    // pipeline: ex = exp(x[t]) for current t; xn1 = x[t+1]; xn2 = x[t+2]
    float ex  = __expf(xp[NC + lane]);
    float xn1 = xp[2 * NC + lane];
    float xn2 = xp[3 * NC + lane];

    for (int t = 1; t < len; ++t) {
        // --- off-chain: prefetch x[t+3], next exp, rescale factors
        int t3 = t + 3; if (t3 > SL - 1) t3 = SL - 1;
        float xnew = xp[(size_t)t3 * NC + lane];
        float exn = __expf(xn1);

        float m  = rflf(q);
        float rm = __builtin_amdgcn_rcpf(m);
        float ex_eff = ex * rm;
        base += __logf(m);

        // --- publish q to the 8 permuted copies (2-way banked writes: free)
#pragma unroll
        for (int k = 0; k < 8; ++k) lds[qaddr[k]] = q;

        // --- matvec: 16 granules, E and q read at identical positions
        float a0 = 0.f, a1 = 0.f, a2 = 0.f, a3 = 0.f;
        float a4 = 0.f, a5 = 0.f, a6 = 0.f, a7 = 0.f;
#pragma unroll
        for (int j = 0; j < 16; j += 2) {
            float4 ev0 = *(const float4*)(Erow + 4 * j);
            float4 qv0 = *(const float4*)(Qrow + 4 * j);
            float4 ev1 = *(const float4*)(Erow + 4 * (j + 1));
            float4 qv1 = *(const float4*)(Qrow + 4 * (j + 1));
            a0 = fmaf(qv0.x, ev0.x, a0);
            a1 = fmaf(qv0.y, ev0.y, a1);
            a2 = fmaf(qv0.z, ev0.z, a2);
            a3 = fmaf(qv0.w, ev0.w, a3);
            a4 = fmaf(qv1.x, ev1.x, a4);
            a5 = fmaf(qv1.y, ev1.y, a5);
            a6 = fmaf(qv1.z, ev1.z, a6);
            a7 = fmaf(qv1.w, ev1.w, a7);
        }
        float s = ((a0 + a1) + (a2 + a3)) + ((a4 + a5) + (a6 + a7));

        q = s * ex_eff;

        // rotate pipeline
        ex = exn; xn1 = xn2; xn2 = xnew;
    }

    // ---- log_norm = base + log(sum_c q_c)
    float qsum = wave_sum(q);
    float log_norm = base + __logf(qsum);
    if (lane == 0) atomicAdd(out, log_norm * (1.0f / BS));
}

// ---------------------------------------------------------------------------
extern "C" void kernel_launch(void* const* d_in, const int* in_sizes, int n_in,
                              void* d_out, int out_size, void* d_ws, size_t ws_size,
                              hipStream_t stream) {
    const float* inputs = (const float*)d_in[0];
    const int*   masks  = (const int*)d_in[1];
    const int*   tags   = (const int*)d_in[2];
    const float* trans  = (const float*)d_in[3];
    float* out = (float*)d_out;

    crf_init_out<<<(1 + NC * NC + 255) / 256, 256, 0, stream>>>(trans, out);
    crf_ub<<<BS, 256, 0, stream>>>(inputs, masks, tags, trans, out);
    crf_fwd<<<BS, 64, 0, stream>>>(inputs, masks, trans, out);
}

// Round 11
// 613.294 us; speedup vs baseline: 1.8588x; 1.8588x over previous
//
#include <hip/hip_runtime.h>

#define BS 512
#define SL 1024
#define NC 64

typedef _Float16 h2 __attribute__((ext_vector_type(2)));
typedef __fp16   p2 __attribute__((ext_vector_type(2)));   // cvt_pkrtz return type

// ---------------------------------------------------------------------------
// Cross-lane / packed helpers (wave64)
// ---------------------------------------------------------------------------
template <int CTRL>
__device__ __forceinline__ float dppf(float x) {
    return __int_as_float(__builtin_amdgcn_mov_dpp(__float_as_int(x), CTRL, 0xF, 0xF, true));
}
__device__ __forceinline__ float rflf(float x) {
    return __int_as_float(__builtin_amdgcn_readfirstlane(__float_as_int(x)));
}
__device__ __forceinline__ void hswap32i(unsigned x, unsigned& r0, unsigned& r1) {
#if __has_builtin(__builtin_amdgcn_permlane32_swap)
    auto r = __builtin_amdgcn_permlane32_swap((int)x, (int)x, false, false);
    r0 = (unsigned)r[0]; r1 = (unsigned)r[1];
#else
    unsigned w = (unsigned)__shfl_xor((int)x, 32, 64);
    bool up = (threadIdx.x & 32) != 0;
    r0 = up ? w : x; r1 = up ? x : w;
#endif
}
__device__ __forceinline__ void halfswap32(float x, float& r0, float& r1) {
    unsigned a, b; hswap32i((unsigned)__float_as_int(x), a, b);
    r0 = __int_as_float((int)a); r1 = __int_as_float((int)b);
}
__device__ __forceinline__ void halfswap16(float x, float& r0, float& r1) {
#if __has_builtin(__builtin_amdgcn_permlane16_swap)
    auto r = __builtin_amdgcn_permlane16_swap(__float_as_int(x), __float_as_int(x), false, false);
    r0 = __int_as_float(r[0]); r1 = __int_as_float(r[1]);
#else
    float w = __int_as_float(__builtin_amdgcn_ds_swizzle(__float_as_int(x), 0x401F)); // xor16
    bool up = (threadIdx.x & 16) != 0;
    r0 = up ? w : x; r1 = up ? x : w;
#endif
}
__device__ __forceinline__ float wave_sum(float x) {
    x += dppf<0xB1>(x);   // xor1
    x += dppf<0x4E>(x);   // xor2
    x += dppf<0x141>(x);  // xor7
    x += dppf<0x140>(x);  // xor15
    float a, c;
    halfswap16(x, a, c); x = a + c;
    halfswap32(x, a, c); x = a + c;
    return x;
}
__device__ __forceinline__ h2 u2h(unsigned u) { union { unsigned u; h2 h; } x; x.u = u; return x.h; }
__device__ __forceinline__ unsigned h2u(h2 h) { union { unsigned u; h2 h; } x; x.h = h; return x.u; }
__device__ __forceinline__ h2 pk(float lo, float hi) {
    union { p2 p; h2 h; } x; x.p = __builtin_amdgcn_cvt_pkrtz(lo, hi); return x.h;
}
__device__ __forceinline__ float fdot2h(h2 a, h2 b, float c) {
#if __has_builtin(__builtin_amdgcn_fdot2)
    return __builtin_amdgcn_fdot2(a, b, c, false);
#else
    return fmaf((float)a[0], (float)b[0], fmaf((float)a[1], (float)b[1], c));
#endif
}

// ---------------------------------------------------------------------------
// Kernel 1: out[0] = 0 (loss acc), out[1..4096] = transitions copy
// ---------------------------------------------------------------------------
__global__ __launch_bounds__(256) void crf_init_out(const float* __restrict__ trans,
                                                    float* __restrict__ out) {
    int idx = blockIdx.x * 256 + threadIdx.x;
    if (idx == 0) out[0] = 0.0f;
    if (idx < NC * NC) out[1 + idx] = trans[idx];
}

// ---------------------------------------------------------------------------
// Kernel 2: unary + binary score sums (fully parallel). Adds -(u+b)/BS to out.
// ---------------------------------------------------------------------------
__global__ __launch_bounds__(256) void crf_ub(const float* __restrict__ inputs,
                                              const int* __restrict__ masks,
                                              const int* __restrict__ tags,
                                              const float* __restrict__ trans,
                                              float* __restrict__ out) {
    const int b = blockIdx.x;
    const int tid = threadIdx.x;
    const int* tg = tags + (size_t)b * SL;
    const int* mk = masks + (size_t)b * SL;
    const float* xb = inputs + (size_t)b * SL * NC;

    float acc = 0.0f;
    const int t0 = tid * 4;
    int tprev = (t0 > 0) ? tg[t0 - 1] : 0;
#pragma unroll
    for (int j = 0; j < 4; ++j) {
        int t = t0 + j;
        int tgt = tg[t];
        if (mk[t] == 0) {
            acc += xb[(size_t)t * NC + tgt];
            if (t > 0) acc += trans[tprev * NC + tgt];
        }
        tprev = tgt;
    }
    acc = wave_sum(acc);
    __shared__ float r[4];
    if ((tid & 63) == 0) r[tid >> 6] = acc;
    __syncthreads();
    if (tid == 0) atomicAdd(out, -(r[0] + r[1] + r[2] + r[3]) * (1.0f / BS));
}

// ---------------------------------------------------------------------------
// Kernel 3: forward recurrence. One wave per batch, lane c owns class c.
//   q'_c = (sum_i q_i * E[i][c]) * exp(x_c) / m,   base += log(m)
// E = exp(T) as 32 packed fp16-pairs per lane (~90 live VGPRs -> resident).
// q gathered as 32 packed pairs: 1 cvt_pkrtz + 1 permlane32_swap +
// 30 ds_swizzle (lane crossbar, no LDS). MACs via v_dot2_f32_f16 (f32 acc).
// Adds +log_norm/BS to out.
// ---------------------------------------------------------------------------
__global__ __launch_bounds__(64)
void crf_fwd(const float* __restrict__ inputs,
             const int* __restrict__ masks,
             const float* __restrict__ trans,
             float* __restrict__ out) {
    const int b = blockIdx.x;
    const int lane = threadIdx.x;
    const float* __restrict__ xp = inputs + (size_t)b * SL * NC;

    // ---- len = lengths[b] via ballot popcount (masks monotone)
    int len = 0;
#pragma unroll
    for (int k = 0; k < SL / NC; ++k) {
        unsigned long long bal = __ballot(masks[(size_t)b * SL + k * NC + lane] == 0);
        len += __popcll(bal);
    }

    // ---- probe permlane32_swap half-assignment convention
    unsigned H0, H1;
    {
        unsigned p0, p1;
        hswap32i((unsigned)lane, p0, p1);
        H0 = __builtin_amdgcn_readfirstlane((int)p0) & 32u;
        H1 = __builtin_amdgcn_readfirstlane((int)p1) & 32u;
    }

    // ---- E packed: Epk[f*16+k] pairs classes {i0,i0+1}, i0=(Hf|((lane&31)^2k))&~1
    // Component order matches q-pack parity: even lane (lo=even cls, hi=odd),
    // odd lane swapped.
    h2 Epk[32];
    const int par = lane & 1;
#pragma unroll
    for (int f = 0; f < 2; ++f) {
        unsigned Hf = f ? H1 : H0;
#pragma unroll
        for (int k = 0; k < 16; ++k) {
            int srcl = (lane & 31) ^ (2 * k);
            int i0 = (int)((Hf | (unsigned)srcl) & ~1u);
            float e0 = __expf(trans[i0 * NC + lane]);
            float e1 = __expf(trans[(i0 | 1) * NC + lane]);
            float lo = par ? e1 : e0;
            float hi = par ? e0 : e1;
            Epk[f * 16 + k] = pk(lo, hi);
        }
    }

    // ---- t = 0
    float x0 = xp[lane];
    float base = rflf(x0);
    float q = __expf(x0 - base);

    // pipeline: ex = exp(x[t]); xn1 = x[t+1]; xn2 = x[t+2]  (len >= 512)
    float ex  = __expf(xp[NC + lane]);
    float xn1 = xp[2 * NC + lane];
    float xn2 = xp[3 * NC + lane];

#define SWZD(W, K) u2h((unsigned)__builtin_amdgcn_ds_swizzle((int)(W), (((K) * 2) << 10) | 0x1F))

    for (int t = 1; t < len; ++t) {
        // --- off-chain: prefetch x[t+3], next exp, rescale factors
        int t3 = t + 3; if (t3 > SL - 1) t3 = SL - 1;
        float xnew = xp[(size_t)t3 * NC + lane];
        float exn = __expf(xn1);

        float m  = rflf(q);
        float rm = __builtin_amdgcn_rcpf(m);
        float ex_eff = ex * rm;
        base += __logf(m);

        // --- pack q into a fp16 pair (order matches Epk per-lane parity)
        float qn = dppf<0xB1>(q);                     // q of lane^1
        unsigned Pu = h2u(pk(q, qn));

        // --- gather: both 32-halves, then xor-swizzles within 32
        unsigned W0, W1;
        hswap32i(Pu, W0, W1);

        float a0 = 0.f, a1 = 0.f, a2 = 0.f, a3 = 0.f;
        float a4 = 0.f, a5 = 0.f, a6 = 0.f, a7 = 0.f;

        a0 = fdot2h(u2h(W0), Epk[0], a0);
        a1 = fdot2h(SWZD(W0, 1),  Epk[1],  a1);
        a2 = fdot2h(SWZD(W0, 2),  Epk[2],  a2);
        a3 = fdot2h(SWZD(W0, 3),  Epk[3],  a3);
        a4 = fdot2h(SWZD(W0, 4),  Epk[4],  a4);
        a5 = fdot2h(SWZD(W0, 5),  Epk[5],  a5);
        a6 = fdot2h(SWZD(W0, 6),  Epk[6],  a6);
        a7 = fdot2h(SWZD(W0, 7),  Epk[7],  a7);
        a0 = fdot2h(SWZD(W0, 8),  Epk[8],  a0);
        a1 = fdot2h(SWZD(W0, 9),  Epk[9],  a1);
        a2 = fdot2h(SWZD(W0, 10), Epk[10], a2);
        a3 = fdot2h(SWZD(W0, 11), Epk[11], a3);
        a4 = fdot2h(SWZD(W0, 12), Epk[12], a4);
        a5 = fdot2h(SWZD(W0, 13), Epk[13], a5);
        a6 = fdot2h(SWZD(W0, 14), Epk[14], a6);
        a7 = fdot2h(SWZD(W0, 15), Epk[15], a7);

        a0 = fdot2h(u2h(W1), Epk[16], a0);
        a1 = fdot2h(SWZD(W1, 1),  Epk[17], a1);
        a2 = fdot2h(SWZD(W1, 2),  Epk[18], a2);
        a3 = fdot2h(SWZD(W1, 3),  Epk[19], a3);
        a4 = fdot2h(SWZD(W1, 4),  Epk[20], a4);
        a5 = fdot2h(SWZD(W1, 5),  Epk[21], a5);
        a6 = fdot2h(SWZD(W1, 6),  Epk[22], a6);
        a7 = fdot2h(SWZD(W1, 7),  Epk[23], a7);
        a0 = fdot2h(SWZD(W1, 8),  Epk[24], a0);
        a1 = fdot2h(SWZD(W1, 9),  Epk[25], a1);
        a2 = fdot2h(SWZD(W1, 10), Epk[26], a2);
        a3 = fdot2h(SWZD(W1, 11), Epk[27], a3);
        a4 = fdot2h(SWZD(W1, 12), Epk[28], a4);
        a5 = fdot2h(SWZD(W1, 13), Epk[29], a5);
        a6 = fdot2h(SWZD(W1, 14), Epk[30], a6);
        a7 = fdot2h(SWZD(W1, 15), Epk[31], a7);

        float s = ((a0 + a1) + (a2 + a3)) + ((a4 + a5) + (a6 + a7));
        q = s * ex_eff;

        // rotate pipeline
        ex = exn; xn1 = xn2; xn2 = xnew;
    }
#undef SWZD

    // ---- log_norm = base + log(sum_c q_c)
    float qsum = wave_sum(q);
    float log_norm = base + __logf(qsum);
    if (lane == 0) atomicAdd(out, log_norm * (1.0f / BS));
}

// ---------------------------------------------------------------------------
extern "C" void kernel_launch(void* const* d_in, const int* in_sizes, int n_in,
                              void* d_out, int out_size, void* d_ws, size_t ws_size,
                              hipStream_t stream) {
    const float* inputs = (const float*)d_in[0];
    const int*   masks  = (const int*)d_in[1];
    const int*   tags   = (const int*)d_in[2];
    const float* trans  = (const float*)d_in[3];
    float* out = (float*)d_out;

    crf_init_out<<<(1 + NC * NC + 255) / 256, 256, 0, stream>>>(trans, out);
    crf_ub<<<BS, 256, 0, stream>>>(inputs, masks, tags, trans, out);
    crf_fwd<<<BS, 64, 0, stream>>>(inputs, masks, trans, out);
}